// Round 4
// baseline (325.102 us; speedup 1.0000x reference)
//
#include <hip/hip_runtime.h>

#define NF 64
#define ND 32
#define NPAIR 2016

typedef __attribute__((ext_vector_type(8))) short bf16x8;
typedef __attribute__((ext_vector_type(4))) float f32x4;

// One sample per wave, 4 waves per block. NO LDS: each lane loads its MFMA
// fragment (32 contiguous bytes of its sample rows) straight from global.
// The wave's 8 dwordx4 loads tile the 64x32 fp32 sample exactly once; the
// two loads of a row hit the same 64B lines, so L1 gives full line use.
__global__ __launch_bounds__(256, 8) void ip_gram_mfma(
    const float* __restrict__ in, float* __restrict__ out) {

    const int t = threadIdx.x;
    const int w = t >> 6;
    const int l = t & 63;
    const int s = blockIdx.x * 4 + w;

    const int q = l >> 4;    // k-block: this lane covers k = 8q..8q+7
    const int m = l & 15;    // row within each 16-row block

    const float* src = in + (size_t)s * (NF * ND) + (q << 3);

    // ---- direct fragment load + fp32 -> bf16 hi/lo split (exact residual) ----
    bf16x8 fhi[4], flo[4];
    #pragma unroll
    for (int r = 0; r < 4; ++r) {
        const float* rowp = src + (r * 16 + m) * ND;
        float4 v0 = ((const float4*)rowp)[0];
        float4 v1 = ((const float4*)rowp)[1];
        float xv[8] = {v0.x, v0.y, v0.z, v0.w, v1.x, v1.y, v1.z, v1.w};
        #pragma unroll
        for (int e = 0; e < 8; ++e) {
            unsigned xb = __builtin_bit_cast(unsigned, xv[e]);
            fhi[r][e] = (short)(xb >> 16);                         // truncate -> hi
            float hf = __builtin_bit_cast(float, xb & 0xFFFF0000u);
            float lf = xv[e] - hf;                                 // exact residual
            flo[r][e] = (short)(__builtin_bit_cast(unsigned, lf) >> 16);
        }
    }

    // ---- upper tiles: D = Xhi*Xhi^T + Xhi*Xlo^T + Xlo*Xhi^T ----
    // Fragment serves as BOTH A and B (gram). C/D: row = q*4 + reg, col = m.
    float* dst = out + (size_t)s * NPAIR;
    #pragma unroll
    for (int ti = 0; ti < 4; ++ti) {
        #pragma unroll
        for (int tj = ti; tj < 4; ++tj) {
            f32x4 c = {0.f, 0.f, 0.f, 0.f};
            c = __builtin_amdgcn_mfma_f32_16x16x32_bf16(fhi[ti], fhi[tj], c, 0, 0, 0);
            c = __builtin_amdgcn_mfma_f32_16x16x32_bf16(fhi[ti], flo[tj], c, 0, 0, 0);
            c = __builtin_amdgcn_mfma_f32_16x16x32_bf16(flo[ti], fhi[tj], c, 0, 0, 0);
            int j = tj * 16 + m;
            #pragma unroll
            for (int r = 0; r < 4; ++r) {
                int i = ti * 16 + (q << 2) + r;
                if (ti < tj || j > i) {
                    int p = ((i * (127 - i)) >> 1) + j - i - 1;
                    __builtin_nontemporal_store(c[r], &dst[p]);   // write-once stream
                }
            }
        }
    }
}

extern "C" void kernel_launch(void* const* d_in, const int* in_sizes, int n_in,
                              void* d_out, int out_size, void* d_ws, size_t ws_size,
                              hipStream_t stream) {
    const float* in = (const float*)d_in[0];
    float* out = (float*)d_out;
    const int nsamples = in_sizes[0] / (NF * ND);   // 16384
    ip_gram_mfma<<<nsamples / 4, 256, 0, stream>>>(in, out);
}

// Round 5
// 248.042 us; speedup vs baseline: 1.3107x; 1.3107x over previous
//
#include <hip/hip_runtime.h>

#define NF 64
#define ND 32
#define NPAIR 2016

typedef __attribute__((ext_vector_type(8))) short bf16x8;
typedef __attribute__((ext_vector_type(4))) float f32x4;

// One sample per wave, 4 waves per block. NO LDS: each lane loads its MFMA
// fragment (32 contiguous bytes of its sample rows) straight from global.
// Plain (cached) stores: the scattered 4-B stores of the packed triangle
// are write-combined by L2 — measured WRITE_SIZE == output size in R0.
// Nontemporal stores broke that (1.84x write amplification, R4).
__global__ __launch_bounds__(256, 8) void ip_gram_mfma(
    const float* __restrict__ in, float* __restrict__ out) {

    const int t = threadIdx.x;
    const int w = t >> 6;
    const int l = t & 63;
    const int s = blockIdx.x * 4 + w;

    const int q = l >> 4;    // k-block: this lane covers k = 8q..8q+7
    const int m = l & 15;    // row within each 16-row block

    const float* src = in + (size_t)s * (NF * ND) + (q << 3);

    // ---- direct fragment load + fp32 -> bf16 hi/lo split (exact residual) ----
    bf16x8 fhi[4], flo[4];
    #pragma unroll
    for (int r = 0; r < 4; ++r) {
        const float* rowp = src + (r * 16 + m) * ND;
        float4 v0 = ((const float4*)rowp)[0];
        float4 v1 = ((const float4*)rowp)[1];
        float xv[8] = {v0.x, v0.y, v0.z, v0.w, v1.x, v1.y, v1.z, v1.w};
        #pragma unroll
        for (int e = 0; e < 8; ++e) {
            unsigned xb = __builtin_bit_cast(unsigned, xv[e]);
            fhi[r][e] = (short)(xb >> 16);                         // truncate -> hi
            float hf = __builtin_bit_cast(float, xb & 0xFFFF0000u);
            float lf = xv[e] - hf;                                 // exact residual
            flo[r][e] = (short)(__builtin_bit_cast(unsigned, lf) >> 16);
        }
    }

    // ---- upper tiles: D = Xhi*Xhi^T + Xhi*Xlo^T + Xlo*Xhi^T ----
    // Fragment serves as BOTH A and B (gram). C/D: row = q*4 + reg, col = m.
    float* dst = out + (size_t)s * NPAIR;
    #pragma unroll
    for (int ti = 0; ti < 4; ++ti) {
        #pragma unroll
        for (int tj = ti; tj < 4; ++tj) {
            f32x4 c = {0.f, 0.f, 0.f, 0.f};
            c = __builtin_amdgcn_mfma_f32_16x16x32_bf16(fhi[ti], fhi[tj], c, 0, 0, 0);
            c = __builtin_amdgcn_mfma_f32_16x16x32_bf16(fhi[ti], flo[tj], c, 0, 0, 0);
            c = __builtin_amdgcn_mfma_f32_16x16x32_bf16(flo[ti], fhi[tj], c, 0, 0, 0);
            int j = tj * 16 + m;
            #pragma unroll
            for (int r = 0; r < 4; ++r) {
                int i = ti * 16 + (q << 2) + r;
                if (ti < tj || j > i) {
                    int p = ((i * (127 - i)) >> 1) + j - i - 1;
                    dst[p] = c[r];                       // cached store: L2 merges
                }
            }
        }
    }
}

extern "C" void kernel_launch(void* const* d_in, const int* in_sizes, int n_in,
                              void* d_out, int out_size, void* d_ws, size_t ws_size,
                              hipStream_t stream) {
    const float* in = (const float*)d_in[0];
    float* out = (float*)d_out;
    const int nsamples = in_sizes[0] / (NF * ND);   // 16384
    ip_gram_mfma<<<nsamples / 4, 256, 0, stream>>>(in, out);
}

// Round 10
// 232.890 us; speedup vs baseline: 1.3960x; 1.0651x over previous
//
#include <hip/hip_runtime.h>

#define NF 64
#define ND 32
#define NPAIR 2016

typedef __attribute__((ext_vector_type(8))) short bf16x8;
typedef __attribute__((ext_vector_type(4))) float f32x4;

// One sample per wave, 4 waves/block. Loads: each lane pulls its MFMA fragment
// (32 contiguous bytes of its sample rows) straight from global (validated R5:
// VGPR 32, occupancy 70%). Stores: R0/R5 showed the scattered 4-B triangle
// stores are the shared ~90 us wall (marginal write BW ~1.1 TB/s vs 6.4 TB/s
// for coalesced fills). Fix: stage the 2016-float row in wave-private LDS,
// then 8 fully-coalesced dwordx4 stores of the contiguous 8064-B block.
__global__ __launch_bounds__(256, 5) void ip_gram_mfma(
    const float* __restrict__ in, float* __restrict__ out) {

    __shared__ float obuf[4][NPAIR];   // 32256 B -> 5 blocks/CU; wave-private, no barriers

    const int t = threadIdx.x;
    const int w = t >> 6;
    const int l = t & 63;
    const int s = blockIdx.x * 4 + w;

    const int q = l >> 4;    // k-block: this lane covers k = 8q..8q+7
    const int m = l & 15;    // row within each 16-row block

    const float* src = in + (size_t)s * (NF * ND) + (q << 3);

    // ---- direct fragment load + fp32 -> bf16 hi/lo split (exact residual) ----
    bf16x8 fhi[4], flo[4];
    #pragma unroll
    for (int r = 0; r < 4; ++r) {
        const float* rowp = src + (r * 16 + m) * ND;
        float4 v0 = ((const float4*)rowp)[0];
        float4 v1 = ((const float4*)rowp)[1];
        float xv[8] = {v0.x, v0.y, v0.z, v0.w, v1.x, v1.y, v1.z, v1.w};
        #pragma unroll
        for (int e = 0; e < 8; ++e) {
            unsigned xb = __builtin_bit_cast(unsigned, xv[e]);
            fhi[r][e] = (short)(xb >> 16);                         // truncate -> hi
            float hf = __builtin_bit_cast(float, xb & 0xFFFF0000u);
            float lf = xv[e] - hf;                                 // exact residual
            flo[r][e] = (short)(__builtin_bit_cast(unsigned, lf) >> 16);
        }
    }

    // ---- upper tiles: D = Xhi*Xhi^T + Xhi*Xlo^T + Xlo*Xhi^T -> LDS row ----
    // Fragment serves as BOTH A and B (gram). C/D: row = q*4 + reg, col = m.
    float* __restrict__ ob = obuf[w];
    #pragma unroll
    for (int ti = 0; ti < 4; ++ti) {
        #pragma unroll
        for (int tj = ti; tj < 4; ++tj) {
            f32x4 c = {0.f, 0.f, 0.f, 0.f};
            c = __builtin_amdgcn_mfma_f32_16x16x32_bf16(fhi[ti], fhi[tj], c, 0, 0, 0);
            c = __builtin_amdgcn_mfma_f32_16x16x32_bf16(fhi[ti], flo[tj], c, 0, 0, 0);
            c = __builtin_amdgcn_mfma_f32_16x16x32_bf16(flo[ti], fhi[tj], c, 0, 0, 0);
            int j = tj * 16 + m;
            #pragma unroll
            for (int r = 0; r < 4; ++r) {
                int i = ti * 16 + (q << 2) + r;
                if (ti < tj || j > i) {
                    int p = ((i * (127 - i)) >> 1) + j - i - 1;
                    ob[p] = c[r];
                }
            }
        }
    }

    // ---- coalesced epilogue: contiguous 8064-B sample row, dwordx4 stores ----
    float4* __restrict__ dst4 = (float4*)(out + (size_t)s * NPAIR);  // 8064 = 504*16: 16B-aligned
    const float4* __restrict__ ob4 = (const float4*)ob;
    #pragma unroll
    for (int it = 0; it < 8; ++it) {
        int idx4 = l + (it << 6);
        if (idx4 < NPAIR / 4) {            // 504 float4s (last iter: 56/64 lanes)
            dst4[idx4] = ob4[idx4];
        }
    }
}

extern "C" void kernel_launch(void* const* d_in, const int* in_sizes, int n_in,
                              void* d_out, int out_size, void* d_ws, size_t ws_size,
                              hipStream_t stream) {
    const float* in = (const float*)d_in[0];
    float* out = (float*)d_out;
    const int nsamples = in_sizes[0] / (NF * ND);   // 16384
    ip_gram_mfma<<<nsamples / 4, 256, 0, stream>>>(in, out);
}